// Round 9
// baseline (1525.850 us; speedup 1.0000x reference)
//
#include <hip/hip_runtime.h>

typedef float f32x4 __attribute__((ext_vector_type(4)));
typedef _Float16 f16x8 __attribute__((ext_vector_type(8)));
typedef _Float16 f16x4 __attribute__((ext_vector_type(4)));
typedef _Float16 f16x2 __attribute__((ext_vector_type(2)));
typedef int i32x4 __attribute__((ext_vector_type(4)));
typedef int i32x2 __attribute__((ext_vector_type(2)));

#define B_TOT   1024
#define D_DIM   128
#define N_STEPS 500
#define ROWS    4
#define WAVES   8

#define HSTR    272                  // bytes per hist row (128 f16 + 16B pad)
#define HSLOT   (8 * HSTR)           // 8 rows: {x_hi b0-3, x_lo b0-3}
#define ZOFF    (11 * HSLOT)         // zero region: 8 rows of zeros
#define BOUNCE  (ZOFF + HSLOT)       // per-wave h handoff: [wave][batch][64 hi | 64 lo] f16
#define BWSTR   1088                 // bounce wave stride (4 rows * 272)
#define SLABOFF (BOUNCE + WAVES * BWSTR)
#define SBSTR   544                  // slab batch stride (bytes)
#define SWSTR   (4 * SBSTR)          // slab wave-slot stride
#define LDSSZ   (SLABOFF + WAVES * SWSTR)   // 52224 B

static __device__ __forceinline__ float tanh_fast(float x) {
    float e = __builtin_amdgcn_exp2f(x * 2.885390081777927f);
    return 1.0f - 2.0f * __builtin_amdgcn_rcpf(e + 1.0f);
}
static __device__ __forceinline__ int packh(_Float16 a, _Float16 b) {
    f16x2 p = (f16x2){a, b};
    return __builtin_bit_cast(int, p);
}
// LDS-only barrier (global stores may stay in flight)
static __device__ __forceinline__ void barrier_lds() {
    asm volatile("s_waitcnt lgkmcnt(0)" ::: "memory");
    __builtin_amdgcn_s_barrier();
}

__global__ __launch_bounds__(512, 2) void ndde_kernel(
    const float* __restrict__ x0, const float* __restrict__ tau,
    const float* __restrict__ W1, const float* __restrict__ b1,
    const float* __restrict__ W2, const float* __restrict__ b2,
    float* __restrict__ out)
{
    __shared__ __align__(16) char smem[LDSSZ];

    const int tid = threadIdx.x;
    const int w   = tid >> 6;
    const int l   = tid & 63;
    const int g   = l >> 4;
    const int l15 = l & 15;
    const int b4  = l15 & 3;
    const bool bval = (l15 < 4);       // lanes carrying a real batch column
    const int r0  = blockIdx.x * ROWS;
    const int rb  = tid >> 7;          // epilogue identity: batch
    const int rd  = tid & 127;         // and d-column

    const float dtv = tau[0] * 0.1f;

    // ---------- weights -> AGPR-pinned fragments (fp16) ----------
    // GEMM1 A: w1s[nt][ks] row = h 64w+16nt+l15, k-col = 32ks+8g+j (x: ks0-3, y: ks4-7)
    // GEMM2 A: w2s[mt][s]  row = d 16mt+l15,    k-col = 64w+32s+8g+j
    i32x4 w1s[4][8];
    i32x4 w2s[8][2];
    i32x2 wbs[4];      // bias A (16x16x16): k rows {wh, wl, wh, b1}

#pragma unroll
    for (int nt = 0; nt < 4; ++nt) {
        const int hr = 64 * w + 16 * nt + l15;
        const float* wr = W1 + (long)hr * 257;
#pragma unroll
        for (int ks = 0; ks < 8; ++ks) {
            const int c0 = 32 * ks + 8 * g;
            f16x8 f;
#pragma unroll
            for (int j = 0; j < 8; ++j) f[j] = (_Float16)wr[c0 + j];
            w1s[nt][ks] = __builtin_bit_cast(i32x4, f);
        }
        float wt = wr[256];
        _Float16 wh = (_Float16)wt;
        _Float16 wl = (_Float16)(wt - (float)wh);
        f16x4 ab = (f16x4){0, 0, 0, 0};
        if (l < 16) ab = (f16x4){wh, wl, wh, (_Float16)b1[hr]};
        wbs[nt] = __builtin_bit_cast(i32x2, ab);
    }
#pragma unroll
    for (int mt = 0; mt < 8; ++mt) {
        const float* wr = W2 + (long)(16 * mt + l15) * 512;
#pragma unroll
        for (int s = 0; s < 2; ++s) {
            const int c0 = 64 * w + 32 * s + 8 * g;
            f16x8 f;
#pragma unroll
            for (int j = 0; j < 8; ++j) f[j] = (_Float16)wr[c0 + j];
            w2s[mt][s] = __builtin_bit_cast(i32x4, f);
        }
    }
    // pin to AGPRs: MFMA reads A from AGPR directly; VALU never touches these
#pragma unroll
    for (int nt = 0; nt < 4; ++nt) {
#pragma unroll
        for (int ks = 0; ks < 8; ++ks) asm volatile("" : "+a"(w1s[nt][ks]));
        asm volatile("" : "+a"(wbs[nt]));
    }
#pragma unroll
    for (int mt = 0; mt < 8; ++mt) {
        asm volatile("" : "+a"(w2s[mt][0]));
        asm volatile("" : "+a"(w2s[mt][1]));
    }

    const float b2v = b2[rd];
    float xo = x0[(long)(r0 + rb) * D_DIM + rd];

    // ---------- init: hist ring, zero region, out[0] ----------
    {
        _Float16 hh = (_Float16)xo;
        _Float16 hl = (_Float16)(xo - (float)hh);
        for (int s = 0; s < 11; ++s) {
            char* sl = smem + s * HSLOT;
            *(short*)(sl + rb * HSTR + 2 * rd)       = __builtin_bit_cast(short, hh);
            *(short*)(sl + (4 + rb) * HSTR + 2 * rd) = __builtin_bit_cast(short, hl);
        }
        if (tid < 544) *(int*)(smem + ZOFF + 4 * tid) = 0;
        out[(long)(r0 + rb) * D_DIM + rd] = xo;
    }
    __syncthreads();

    // invariant offsets
    const int hoff    = 16 * g;                                    // + 64*ks within row
    const int rowOff  = b4 * HSTR;                                 // batch row (or zero row)
    const char* bnc   = smem + BOUNCE + w * BWSTR + b4 * 272;      // GEMM2 B base (dup for l15>=4)
    const char* bncW  = smem + BOUNCE + w * BWSTR + b4 * 272;      // writer base (l15<4 only)
    const int slabWr  = SLABOFF + w * SWSTR + l15 * SBSTR + 16 * g;  // + 64*mt  (l15<4)
    const int slabRd  = SLABOFF + rb * SBSTR + 4 * rd;               // + sv*SWSTR
    float* po = out + (long)(B_TOT * D_DIM) + (long)(r0 + rb) * D_DIM + rd;

    int cur = 0, ys = 1;

#pragma clang loop unroll(disable)
    for (int n = 0; n < N_STEPS; ++n) {
        // ---- per-step bias B-frag (16x16x16): cols 0-3, k = {th, th, tl, 1} ----
        const float t = (float)n * dtv;
        _Float16 th = (_Float16)t;
        _Float16 tl = (_Float16)(t - (float)th);
        int tb0 = (l < 4) ? packh(th, th) : 0;
        int tb1 = (l < 4) ? packh(tl, (_Float16)1.0f) : 0;
        f16x4 bt = __builtin_bit_cast(f16x4, (i32x2){tb0, tb1});

        // per-step hist bases: real batch rows for lanes 0-3, zero rows otherwise
        const char* xb = smem + (bval ? cur * HSLOT : ZOFF) + rowOff;
        const char* yb = smem + (bval ? ys  * HSLOT : ZOFF) + rowOff;

        // ---- GEMM1: acc1[nt] = bias + W1x@(x_hi,x_lo) + W1y@(y_hi,y_lo) ----
        f32x4 acc1[4];
        const f32x4 zz = (f32x4){0.f, 0.f, 0.f, 0.f};
#pragma unroll
        for (int nt = 0; nt < 4; ++nt)
            acc1[nt] = __builtin_amdgcn_mfma_f32_16x16x16f16(
                __builtin_bit_cast(f16x4, wbs[nt]), bt, zz, 0, 0, 0);

#pragma unroll
        for (int ks = 0; ks < 4; ++ks) {
            f16x8 bh = *(const f16x8*)(xb + hoff + 64 * ks);
            f16x8 bl = *(const f16x8*)(xb + 4 * HSTR + hoff + 64 * ks);
#pragma unroll
            for (int nt = 0; nt < 4; ++nt)
                acc1[nt] = __builtin_amdgcn_mfma_f32_16x16x32_f16(
                    __builtin_bit_cast(f16x8, w1s[nt][ks]), bh, acc1[nt], 0, 0, 0);
#pragma unroll
            for (int nt = 0; nt < 4; ++nt)
                acc1[nt] = __builtin_amdgcn_mfma_f32_16x16x32_f16(
                    __builtin_bit_cast(f16x8, w1s[nt][ks]), bl, acc1[nt], 0, 0, 0);
        }
#pragma unroll
        for (int ks = 0; ks < 4; ++ks) {
            f16x8 bh = *(const f16x8*)(yb + hoff + 64 * ks);
            f16x8 bl = *(const f16x8*)(yb + 4 * HSTR + hoff + 64 * ks);
#pragma unroll
            for (int nt = 0; nt < 4; ++nt)
                acc1[nt] = __builtin_amdgcn_mfma_f32_16x16x32_f16(
                    __builtin_bit_cast(f16x8, w1s[nt][ks + 4]), bh, acc1[nt], 0, 0, 0);
#pragma unroll
            for (int nt = 0; nt < 4; ++nt)
                acc1[nt] = __builtin_amdgcn_mfma_f32_16x16x32_f16(
                    __builtin_bit_cast(f16x8, w1s[nt][ks + 4]), bl, acc1[nt], 0, 0, 0);
        }

        // ---- tanh + hi/lo split, wave-local bounce write (h-rows 16nt+4g+r, batch b4) ----
#pragma unroll
        for (int nt = 0; nt < 4; ++nt) {
            float h0 = tanh_fast(acc1[nt][0]);
            float h1 = tanh_fast(acc1[nt][1]);
            float h2 = tanh_fast(acc1[nt][2]);
            float h3 = tanh_fast(acc1[nt][3]);
            _Float16 p0 = (_Float16)h0, p1 = (_Float16)h1;
            _Float16 p2 = (_Float16)h2, p3 = (_Float16)h3;
            if (bval) {
                char* dst = (char*)bncW + 32 * nt + 8 * g;
                *(i32x2*)dst = (i32x2){packh(p0, p1), packh(p2, p3)};
                *(i32x2*)(dst + 128) = (i32x2){
                    packh((_Float16)(h0 - (float)p0), (_Float16)(h1 - (float)p1)),
                    packh((_Float16)(h2 - (float)p2), (_Float16)(h3 - (float)p3))};
            }
        }
        // wave-local handoff: compiler inserts lgkmcnt for LDS RAW; no barrier needed

        // ---- GEMM2: K-split (this wave's 64 h), k-major hi/lo, N = 4 batches ----
        f16x8 bh0 = *(const f16x8*)(bnc + hoff);
        f16x8 bh1 = *(const f16x8*)(bnc + 64 + hoff);
        f16x8 bl0 = *(const f16x8*)(bnc + 128 + hoff);
        f16x8 bl1 = *(const f16x8*)(bnc + 192 + hoff);
        f32x4 a2[8];
#pragma unroll
        for (int mt = 0; mt < 8; ++mt)
            a2[mt] = __builtin_amdgcn_mfma_f32_16x16x32_f16(
                __builtin_bit_cast(f16x8, w2s[mt][0]), bh0, zz, 0, 0, 0);
#pragma unroll
        for (int mt = 0; mt < 8; ++mt)
            a2[mt] = __builtin_amdgcn_mfma_f32_16x16x32_f16(
                __builtin_bit_cast(f16x8, w2s[mt][1]), bh1, a2[mt], 0, 0, 0);
#pragma unroll
        for (int mt = 0; mt < 8; ++mt)
            a2[mt] = __builtin_amdgcn_mfma_f32_16x16x32_f16(
                __builtin_bit_cast(f16x8, w2s[mt][0]), bl0, a2[mt], 0, 0, 0);
#pragma unroll
        for (int mt = 0; mt < 8; ++mt)
            a2[mt] = __builtin_amdgcn_mfma_f32_16x16x32_f16(
                __builtin_bit_cast(f16x8, w2s[mt][1]), bl1, a2[mt], 0, 0, 0);

        if (bval) {
#pragma unroll
            for (int mt = 0; mt < 8; ++mt)
                *(f32x4*)(smem + slabWr + 64 * mt) = a2[mt];
        }
        barrier_lds();

        // ---- reduce 8 K-split partials + Euler + hist/out emit ----
        float acc = 0.f;
#pragma unroll
        for (int sv = 0; sv < 8; ++sv)
            acc += *(const float*)(smem + slabRd + sv * SWSTR);
        const float xn = fmaf(dtv, acc + b2v, xo);
        xo = xn;
        {
            _Float16 hh = (_Float16)xn;
            _Float16 hl = (_Float16)(xn - (float)hh);
            char* sl = smem + ys * HSLOT;
            *(short*)(sl + rb * HSTR + 2 * rd)       = __builtin_bit_cast(short, hh);
            *(short*)(sl + (4 + rb) * HSTR + 2 * rd) = __builtin_bit_cast(short, hl);
        }
        *po = xn;
        po += B_TOT * D_DIM;

        cur = ys;
        ys  = (ys == 10) ? 0 : ys + 1;
        barrier_lds();
    }
}

extern "C" void kernel_launch(void* const* d_in, const int* in_sizes, int n_in,
                              void* d_out, int out_size, void* d_ws, size_t ws_size,
                              hipStream_t stream) {
    (void)in_sizes; (void)n_in; (void)out_size; (void)d_ws; (void)ws_size;
    const float* x0  = (const float*)d_in[0];
    const float* tau = (const float*)d_in[1];
    const float* W1  = (const float*)d_in[2];
    const float* b1  = (const float*)d_in[3];
    const float* W2  = (const float*)d_in[4];
    const float* b2  = (const float*)d_in[5];
    float* out = (float*)d_out;

    ndde_kernel<<<dim3(B_TOT / ROWS), dim3(64 * WAVES), 0, stream>>>(
        x0, tau, W1, b1, W2, b2, out);
}

// Round 10
// 989.405 us; speedup vs baseline: 1.5422x; 1.5422x over previous
//
#include <hip/hip_runtime.h>

typedef float f32x4 __attribute__((ext_vector_type(4)));
typedef _Float16 f16x8 __attribute__((ext_vector_type(8)));

#define B_TOT   1024
#define D_DIM   128
#define H_DIM   512
#define N_STEPS 500
#define ROWS    4      // batch rows per block
#define WAVES   8      // waves per block

#define HSTRIDE 272                 // bytes per hist row (128 f16 + pad)
#define HSLOT   (8 * HSTRIDE)       // 8 rows (4 hi + 4 lo) per slot
#define BSTRIDE 1056                // bytes per bounce row (512 f16 + pad)
#define LDS_BOUNCE (11 * HSLOT)     // hist occupies [0, 11*HSLOT)
#define LDS_TOTAL  (LDS_BOUNCE + 8 * BSTRIDE)

static __device__ __forceinline__ short f16b(float f) {
    _Float16 h = (_Float16)f;
    return __builtin_bit_cast(short, h);
}
static __device__ __forceinline__ float f16tof(short s) {
    return (float)__builtin_bit_cast(_Float16, s);
}
static __device__ __forceinline__ float tanh_fast(float x) {
    float e = __builtin_amdgcn_exp2f(x * 2.885390081777927f);
    return 1.0f - 2.0f * __builtin_amdgcn_rcpf(e + 1.0f);
}
static __device__ __forceinline__ f32x4 sx32(f32x4 v) {
    f32x4 r;
#pragma unroll
    for (int i = 0; i < 4; ++i) r[i] = __shfl_xor(v[i], 32);
    return r;
}
// dynamic element pick via cndmask tree (no scratch)
static __device__ __forceinline__ float pick(f32x4 v, int g) {
    float lo = (g & 1) ? v[1] : v[0];
    float hi = (g & 1) ? v[3] : v[2];
    return (g & 2) ? hi : lo;
}
// LDS-only barrier (global stores may stay in flight)
static __device__ __forceinline__ void barrier_lds() {
    asm volatile("s_waitcnt lgkmcnt(0)" ::: "memory");
    __builtin_amdgcn_s_barrier();
}

__global__ __launch_bounds__(512, 2) void ndde_kernel(
    const float* __restrict__ x0, const float* __restrict__ tau,
    const float* __restrict__ W1, const float* __restrict__ b1,
    const float* __restrict__ W2, const float* __restrict__ b2,
    float* __restrict__ out)
{
    __shared__ __align__(16) char smem[LDS_TOTAL];

    const int tid = threadIdx.x;
    const int w   = tid >> 6;
    const int l   = tid & 63;
    const int g   = l >> 4;
    const int l15 = l & 15;
    // A-frag row = l15; rows [0-3]=hi b0-3, [4-7]=dup, [8-11]=lo b0-3, [12-15]=dup
    const int ur  = (l15 & 3) | ((l15 >> 3) << 2);   // storage row 0..7
    const int r0  = blockIdx.x * ROWS;
    const int d   = 16 * w + l15;                    // this lane's owned d-col

    const float dtv = tau[0] * 0.1f;

    // ---------------- weights -> registers (fp16, compiler-managed) ----------------
    f16x8 w1f[4][8];   // [nt over 64 h-rows][ks over K=256]  (x: ks0-3, y: ks4-7)
    f16x8 w2f[16];     // [ks over K=512], B-frag cols = d in [16w, 16w+16)
    float b1f[4], w1tf[4];

#pragma unroll
    for (int nt = 0; nt < 4; ++nt) {
        const int hr = 64 * w + 16 * nt + l15;
        const float* wr = W1 + (long)hr * 257;
#pragma unroll
        for (int ks = 0; ks < 8; ++ks) {
            const int c0 = 32 * ks + 8 * g;
            f16x8 f;
#pragma unroll
            for (int j = 0; j < 8; ++j) f[j] = (_Float16)wr[c0 + j];
            w1f[nt][ks] = f;
        }
        b1f[nt]  = b1[hr];
        w1tf[nt] = wr[256];
    }
    {
        const float* wr = W2 + (long)d * 512;
#pragma unroll
        for (int ks = 0; ks < 16; ++ks) {
            const int c0 = 32 * ks + 8 * g;
            f16x8 f;
#pragma unroll
            for (int j = 0; j < 8; ++j) f[j] = (_Float16)wr[c0 + j];
            w2f[ks] = f;
        }
    }
    const float b2v = b2[d];
    float xo = x0[(long)(r0 + g) * D_DIM + d];   // lane-owned state (r=g, d)

    // ---------------- init hist ring + out[0] ----------------
    {
        short hb = f16b(xo);
        short lb = f16b(xo - f16tof(hb));
        for (int s = 0; s < 11; ++s) {
            *(short*)(smem + s * HSLOT + g * HSTRIDE + 2 * d)       = hb;
            *(short*)(smem + s * HSLOT + (g + 4) * HSTRIDE + 2 * d) = lb;
        }
        out[(long)(r0 + g) * D_DIM + d] = xo;
    }
    __syncthreads();

    // per-lane invariant LDS offsets
    const int histRd   = ur * HSTRIDE + 16 * g;                              // + slot*HSLOT + 64*ks
    const int bounceRd = LDS_BOUNCE + ur * BSTRIDE + ((16 * g) ^ ((ur & 3) << 4)); // + 64*ks
    const int bwXor    = g << 4;   // write-side XOR (row g)

    float* po = out + (long)(B_TOT * D_DIM) + (long)(r0 + g) * D_DIM + d;

    int cur = 0;   // hist slot holding x_n
    int ys  = 1;   // slot holding y_n = x_{n-10}; overwritten with x_{n+1}

    // ---- prologue: y-part of GEMM1 for step 0 (slot 1 = x0 history) ----
    f32x4 accY[4];
#pragma unroll
    for (int nt = 0; nt < 4; ++nt) accY[nt] = (f32x4){0.f, 0.f, 0.f, 0.f};
    {
        const char* yb = smem + 1 * HSLOT + histRd;
#pragma unroll
        for (int ks = 0; ks < 4; ++ks) {
            f16x8 ya = *(const f16x8*)(yb + 64 * ks);
#pragma unroll
            for (int nt = 0; nt < 4; ++nt)
                accY[nt] = __builtin_amdgcn_mfma_f32_16x16x32_f16(ya, w1f[nt][ks + 4], accY[nt], 0, 0, 0);
        }
    }

#pragma clang loop unroll(disable)
    for (int n = 0; n < N_STEPS; ++n) {
        const float t = (float)n * dtv;

        // -------- GEMM1 x-part (critical path): accY already holds y-part --------
        const char* xb = smem + cur * HSLOT + histRd;
#pragma unroll
        for (int ks = 0; ks < 4; ++ks) {
            f16x8 xa = *(const f16x8*)(xb + 64 * ks);
#pragma unroll
            for (int nt = 0; nt < 4; ++nt)
                accY[nt] = __builtin_amdgcn_mfma_f32_16x16x32_f16(xa, w1f[nt][ks], accY[nt], 0, 0, 0);
        }

        // combine hi+lo rows (lane^32), bias, tanh, write bounce
#pragma unroll
        for (int nt = 0; nt < 4; ++nt) {
            f32x4 c = accY[nt];
            c += sx32(c);
            float hp = pick(c, g) + fmaf(t, w1tf[nt], b1f[nt]);
            float h  = tanh_fast(hp);
            short hh = f16b(h);
            short hl = f16b(h - f16tof(hh));
            const int cb = (2 * (64 * w + 16 * nt + l15)) ^ bwXor;
            *(short*)(smem + LDS_BOUNCE + g * BSTRIDE + cb)       = hh;
            *(short*)(smem + LDS_BOUNCE + (g + 4) * BSTRIDE + cb) = hl;
        }
        barrier_lds();

        // -------- GEMM2: full K=512, 4 independent chains --------
        f32x4 a2c[4];
#pragma unroll
        for (int c = 0; c < 4; ++c) {
            a2c[c] = (f32x4){0.f, 0.f, 0.f, 0.f};
#pragma unroll
            for (int k = 0; k < 4; ++k) {
                f16x8 ha = *(const f16x8*)(smem + bounceRd + 64 * (4 * c + k));
                a2c[c] = __builtin_amdgcn_mfma_f32_16x16x32_f16(ha, w2f[4 * c + k], a2c[c], 0, 0, 0);
            }
        }

        // -------- y-part precompute for step n+1 (hides in GEMM2 shadow) --------
        const int ysN = (ys == 10) ? 0 : ys + 1;   // slot of y_{n+1} = x_{n-9}
#pragma unroll
        for (int nt = 0; nt < 4; ++nt) accY[nt] = (f32x4){0.f, 0.f, 0.f, 0.f};
        {
            const char* yb = smem + ysN * HSLOT + histRd;
#pragma unroll
            for (int ks = 0; ks < 4; ++ks) {
                f16x8 ya = *(const f16x8*)(yb + 64 * ks);
#pragma unroll
                for (int nt = 0; nt < 4; ++nt)
                    accY[nt] = __builtin_amdgcn_mfma_f32_16x16x32_f16(ya, w1f[nt][ks + 4], accY[nt], 0, 0, 0);
            }
        }

        // -------- fold chains + Euler update + emit --------
        f32x4 acc2 = (a2c[0] + a2c[1]) + (a2c[2] + a2c[3]);
        acc2 += sx32(acc2);
        const float o  = pick(acc2, g) + b2v;
        const float xn = fmaf(dtv, o, xo);
        xo = xn;
        {
            short hb = f16b(xn);
            short lb = f16b(xn - f16tof(hb));
            *(short*)(smem + ys * HSLOT + g * HSTRIDE + 2 * d)       = hb;   // x_{n+1} -> slot ys
            *(short*)(smem + ys * HSLOT + (g + 4) * HSTRIDE + 2 * d) = lb;
        }
        *po = xn;
        po += B_TOT * D_DIM;

        cur = ys;
        ys  = ysN;
        barrier_lds();
    }
}

extern "C" void kernel_launch(void* const* d_in, const int* in_sizes, int n_in,
                              void* d_out, int out_size, void* d_ws, size_t ws_size,
                              hipStream_t stream) {
    (void)in_sizes; (void)n_in; (void)out_size; (void)d_ws; (void)ws_size;
    const float* x0  = (const float*)d_in[0];
    const float* tau = (const float*)d_in[1];
    const float* W1  = (const float*)d_in[2];
    const float* b1  = (const float*)d_in[3];
    const float* W2  = (const float*)d_in[4];
    const float* b2  = (const float*)d_in[5];
    float* out = (float*)d_out;

    ndde_kernel<<<dim3(B_TOT / ROWS), dim3(64 * WAVES), 0, stream>>>(
        x0, tau, W1, b1, W2, b2, out);
}